// Round 11
// baseline (506.119 us; speedup 1.0000x reference)
//
#include <hip/hip_runtime.h>
#include <hip/hip_bf16.h>
#include <stdint.h>

// Sizes (fixed by the problem)
#define LDIM 2048
#define BDIM 64
#define HDIM 1024
#define HCDIM 1024
// Compacted rows (mask==1 only): M_c ~ Binomial(131072, .5) ~= 65536 +- 181.
#define CAPROWS 98304   // compacted-row capacity: 180 sigma above the mean

typedef __attribute__((ext_vector_type(8))) short short8;  // 8 bf16 (4 VGPRs)
typedef __attribute__((ext_vector_type(4))) short s16x4;
typedef __attribute__((ext_vector_type(4))) float f32x4;

static __device__ __forceinline__ short f2bf(float f) {
  union { float f; uint32_t u; } a; a.f = f;
  uint32_t r = a.u + 0x7fffu + ((a.u >> 16) & 1u);  // RNE
  return (short)(r >> 16);
}
static __device__ __forceinline__ float bf2f(short s) {
  union { uint32_t u; float f; } a;
  a.u = ((uint32_t)(unsigned short)s) << 16;
  return a.f;
}
static __device__ __forceinline__ float fast_tanh(float x) {
  x = fminf(15.f, fmaxf(-15.f, x));
  float e = __expf(2.f * x);
  return (e - 1.f) * __builtin_amdgcn_rcpf(e + 1.f);
}

// direct-to-LDS 16B async copy (gfx950); dest is wave-uniform base + lane*16
#define GL16(gp, lp) __builtin_amdgcn_global_load_lds(                           \
    (const __attribute__((address_space(1))) void*)(gp),                         \
    (__attribute__((address_space(3))) void*)(lp), 16, 0, 0)

// ---------- Ks: mask scan (1 block, 512 thr) + zero logitsT (no memset pass) ----------
__global__ void scan_mask(const int* __restrict__ mask, int* __restrict__ bases,
                          float* __restrict__ logitsT) {
  __shared__ int sc[512];
  const int t = threadIdx.x;
  const float4 z = {0.f, 0.f, 0.f, 0.f};
  #pragma unroll 4
  for (int i = 0; i < 64; ++i) *(float4*)&logitsT[t * 256 + i * 4] = z;
  int cnt = 0;
  #pragma unroll 8
  for (int b = 0; b < 64; ++b) {
    int4 v = *(const int4*)&mask[b * 2048 + t * 4];
    cnt += v.x + v.y + v.z + v.w;
  }
  sc[t] = cnt;
  __syncthreads();
  for (int off = 1; off < 512; off <<= 1) {
    int v = (t >= off) ? sc[t - off] : 0;
    __syncthreads();
    sc[t] += v;
    __syncthreads();
  }
  bases[t] = sc[t] - cnt;            // exclusive
  if (t == 511) bases[512] = sc[511];
}

// ---------- Kg: gather unmasked rows, f32 -> bf16 (512 blocks x 512 thr) ----------
__global__ void gather_rows(const float* __restrict__ prev, const int* __restrict__ mask,
                            const int* __restrict__ bases, short* __restrict__ A_c,
                            int* __restrict__ cm2m, int* __restrict__ m2cm) {
  __shared__ int smm[256];
  __shared__ int swt[4];
  const int c = blockIdx.x, t = threadIdx.x;
  const int base = bases[c];
  int bit = 0, p = 0, wv = 0;
  if (t < 256) {
    const int m = c * 256 + t;                 // l = m>>6, b = t&63
    bit = (mask[(t & 63) * 2048 + (m >> 6)] != 0);
    unsigned long long bal = __ballot(bit);
    const int lane = t & 63;
    wv = t >> 6;
    p = __popcll(bal & ((1ull << lane) - 1ull));
    if (lane == 0) swt[wv] = (int)__popcll(bal);
  }
  __syncthreads();
  if (t < 256 && bit) {
    int off = p;
    for (int i = 0; i < wv; ++i) off += swt[i];
    const int cm = base + off;
    smm[off] = t;
    if (cm < CAPROWS) {
      cm2m[cm] = c * 256 + t;
      m2cm[c * 256 + t] = cm;
    }
  }
  __syncthreads();
  const int cnt = swt[0] + swt[1] + swt[2] + swt[3];
  const int col = (t & 255) * 4;
  for (int r = (t >> 8); r < cnt; r += 2) {
    const int lm = smm[r];
    const float4 v = *(const float4*)(prev + (((size_t)(c * 256 + lm)) << 10) + col);
    if (base + r < CAPROWS) {
      s16x4 o = { f2bf(v.x), f2bf(v.y), f2bf(v.z), f2bf(v.w) };
      *(s16x4*)&A_c[(((size_t)(base + r)) << 10) + col] = o;
    }
  }
}

// ---------- K1: W_e[:, H:2H] f32 -> Wb2 bf16, FRAGMENT-MAJOR pack (r10) ----------
// (c,k): c16=c>>4, lr=c&15, ks=k>>5, q=(k>>3)&3, r=k&7
//   -> Wb2[(c16*32+ks)*512 + (lr*4+q)*8 + r]  => one coalesced 1KB frag load/wave.
__global__ void convert_we_pack(const float* __restrict__ We, short* __restrict__ Wb2) {
  int g = blockIdx.x * 256 + threadIdx.x;
  int c = g >> 8;
  int j = (g & 255) * 4;
  float4 v = *(const float4*)(We + (size_t)c * 2048 + 1024 + j);
  s16x4 o = { f2bf(v.x), f2bf(v.y), f2bf(v.z), f2bf(v.w) };
  const int off = ((c >> 4) * 32 + (j >> 5)) * 512 + ((c & 15) * 4 + ((j >> 3) & 3)) * 8 + (j & 7);
  *(s16x4*)(Wb2 + off) = o;
}

// ---------- K0: hidbias + zero d_out (block b zeroes out[b]) ----------
__global__ void hidbias_kernel(const float* __restrict__ We, const float* __restrict__ hidden,
                               const float* __restrict__ be, float* __restrict__ hidbias,
                               float* __restrict__ out) {
  __shared__ float wrow[1024];
  int c0 = blockIdx.x * 16;
  int t = threadIdx.x;
  int b = t >> 2, q = t & 3;
  const float4 z = {0.f, 0.f, 0.f, 0.f};
  *(float4*)&out[blockIdx.x * 1024 + t * 4] = z;
  for (int ci = 0; ci < 16; ++ci) {
    int c = c0 + ci;
    *(float4*)&wrow[t * 4] = *(const float4*)&We[(size_t)c * 2048 + t * 4];
    __syncthreads();
    float s0 = 0.f, s1 = 0.f;
    const float* hb = hidden + b * 1024;
    #pragma unroll 8
    for (int j = 0; j < 256; j += 2) {
      int i0 = q + 4 * j;
      s0 += wrow[i0] * hb[i0];
      s1 += wrow[i0 + 4] * hb[i0 + 4];
    }
    float s = s0 + s1;
    s += __shfl_xor(s, 1);
    s += __shfl_xor(s, 2);
    if (q == 0) hidbias[b * 1024 + c] = s + be[c];
    __syncthreads();
  }
}

// ---------- K2: compacted GEMM, 256x128 tile, 4 waves, 2 blocks/CU ----------
// A-only LDS (4 bufs x 16 KB = 64 KiB) + B-frags from L2-resident Wb2 into regs
// (double-buffered sets). 2 co-resident blocks per CU have INDEPENDENT barriers
// -> one block's LDS-read phase overlaps the other's MFMA phase (m114), breaking
// r6's additive LDS->MFMA lockstep (both pipes were ~33% busy, wall 3x pipe floor).
// vs r8's failed 128^2: A-rows stay 256 (staging bytes/FLOP unchanged), B not in LDS.
// vmcnt ledger (STAGE_A = 4 GL16, BLOAD = 4 VMEM): steady queue entering iter ks =
// [A(ks+1):4, B(ks):4, A(ks+2):4]; issue B(ks+1) -> 16; VMW(8) drains A(ks+1)+B(ks).
// Tail: 8 -> 8 -> 4 -> 0. One s_barrier per K-step (4-buffer rotation as r6).
__global__ __launch_bounds__(256, 2) void energy_gemm_2b(
    const short* __restrict__ A_c, const short* __restrict__ Wb2,
    const float* __restrict__ hidbias, const float* __restrict__ Wv,
    const int* __restrict__ bases, const int* __restrict__ cm2m,
    float* __restrict__ logitsT)
{
  __shared__ short As[4][256][32];   // 64 KiB
  __shared__ int sidx[256];
  const int Mc0 = bases[512];
  const int Mc = Mc0 < CAPROWS ? Mc0 : CAPROWS;
  // grid 3072 = 384 mt x 8 nt; mt = (bid>>6)*8 + (bid&7): an m-tile's 8 n-siblings
  // share bid%8 (same XCD); live m-tiles spread across XCDs after early-exit.
  const int mt = ((blockIdx.x >> 6) << 3) + (blockIdx.x & 7);
  const int nt = (blockIdx.x >> 3) & 7;
  if (mt * 256 >= Mc) return;
  const int m0 = mt * 256;
  const int n0 = nt * 128;

  const int tid = threadIdx.x;                    // 256 threads, 4 waves
  const int wave = tid >> 6, lane = tid & 63;
  const int q = lane >> 4, lr = lane & 15;
  const int wr = wave >> 1, wc = wave & 1;        // 2M x 2N, wave tile 128x64

  // A staging: thread t -> rows r0 + 64*i (i=0..3); 16B chunk (t&3)^((r0>>1)&3)
  const int r0 = tid >> 2;                        // 0..63
  const int c0s = (((tid & 3) ^ ((r0 >> 1) & 3))) * 8;   // invariant under r0+64
  const short* asrc = A_c + (size_t)(m0 + r0) * 1024 + c0s;

#define STAGE_A(buf, ks) do {                                                  \
    const int _ko = (ks) * 32;                                                 \
    GL16(asrc + _ko,          &As[buf][0][0] + tid * 8);                       \
    GL16(asrc + 65536 + _ko,  &As[buf][0][0] + tid * 8 + 2048);                \
    GL16(asrc + 131072 + _ko, &As[buf][0][0] + tid * 8 + 4096);                \
    GL16(asrc + 196608 + _ko, &As[buf][0][0] + tid * 8 + 6144);                \
  } while (0)

  // B-frag base: c16 = (n0 + wc*64 + ni*16)>>4 = nt*8 + wc*4 + ni
  const int c16b = nt * 8 + wc * 4;
  const int lane4 = (lr * 4 + q) * 8;             // per-lane packed offset (shorts)

#define BLOAD(dst, ks) do {                                                    \
    _Pragma("unroll")                                                          \
    for (int ni = 0; ni < 4; ++ni)                                             \
      dst[ni] = *(const short8*)(Wb2 + (size_t)((c16b + ni) * 32 + (ks)) * 512 + lane4); \
  } while (0)

  // swizzled A read chunk: q ^ ((row>>1)&3) = q ^ ((lr>>1)&3)
  const int crd = (q ^ ((lr >> 1) & 3)) * 8;

#define COMPUTE(buf, BSET) do {                                                \
    short8 af[8];                                                              \
    _Pragma("unroll")                                                          \
    for (int mi = 0; mi < 8; ++mi)                                             \
      af[mi] = *(const short8*)&As[buf][wr * 128 + mi * 16 + lr][crd];         \
    __builtin_amdgcn_s_setprio(1);                                             \
    _Pragma("unroll")                                                          \
    for (int mi = 0; mi < 8; ++mi)                                             \
      _Pragma("unroll")                                                        \
      for (int ni = 0; ni < 4; ++ni)                                           \
        acc[mi][ni] = __builtin_amdgcn_mfma_f32_16x16x32_bf16(                 \
            af[mi], BSET[ni], acc[mi][ni], 0, 0, 0);                           \
    __builtin_amdgcn_s_setprio(0);                                             \
  } while (0)

#define VMW8() asm volatile("s_waitcnt vmcnt(8)" ::: "memory")
#define VMW4() asm volatile("s_waitcnt vmcnt(4)" ::: "memory")
#define VMW0() asm volatile("s_waitcnt vmcnt(0)" ::: "memory")
#define BAR()  asm volatile("s_barrier" ::: "memory")

  f32x4 acc[8][4];
  #pragma unroll
  for (int i = 0; i < 8; ++i)
    #pragma unroll
    for (int j = 0; j < 4; ++j) acc[i][j] = (f32x4){0.f, 0.f, 0.f, 0.f};

  short8 bs0[4], bs1[4];   // B(k) lives in set k&1

  // prologue: queue = [A0:4, A1:4, B0:4, A2:4]
  STAGE_A(0, 0);
  STAGE_A(1, 1);
  BLOAD(bs0, 0);
  STAGE_A(2, 2);

#define ITER(ks, CUR, NXT) do {                                                \
    BLOAD(NXT, (ks) + 1);                                                      \
    VMW8(); BAR();                                                             \
    STAGE_A(((ks) + 3) & 3, (ks) + 3);                                         \
    COMPUTE((ks) & 3, CUR);                                                    \
  } while (0)

  #pragma unroll 2
  for (int ks = 0; ks < 28; ks += 2) {
    ITER(ks, bs0, bs1);
    ITER(ks + 1, bs1, bs0);
  }
  // tail: ks = 28..31 (A stages end at 31, B loads end at 31)
  ITER(28, bs0, bs1);                                   // stages A31, loads B29
  { BLOAD(bs0, 30); VMW8(); BAR(); COMPUTE(1, bs1); }   // ks=29
  { BLOAD(bs1, 31); VMW4(); BAR(); COMPUTE(2, bs0); }   // ks=30  (drains A31,B30)
  { VMW0(); BAR(); COMPUTE(3, bs1); }                   // ks=31

#undef ITER
#undef STAGE_A
#undef BLOAD
#undef COMPUTE

  // Epilogue. D frag: col = lr (-> c), row = 4*q + reg (verified r1-r10).
  if (tid < 256) sidx[tid] = (m0 + tid < Mc) ? cm2m[m0 + tid] : -1;
  __syncthreads();

  float wv[4];
  #pragma unroll
  for (int ni = 0; ni < 4; ++ni) wv[ni] = Wv[n0 + wc * 64 + ni * 16 + lr];

  #pragma unroll
  for (int mi = 0; mi < 8; ++mi) {
    #pragma unroll
    for (int r = 0; r < 4; ++r) {
      const int row = wr * 128 + mi * 16 + 4 * q + r;   // within 256-row tile
      const int mm = sidx[row];
      if (mm >= 0) {
        const int b = mm & 63;
        float s = 0.f;
        #pragma unroll
        for (int ni = 0; ni < 4; ++ni) {
          const int c = n0 + wc * 64 + ni * 16 + lr;
          s += fast_tanh(acc[mi][ni][r] + hidbias[b * 1024 + c]) * wv[ni];
        }
        s += __shfl_xor(s, 1);
        s += __shfl_xor(s, 2);
        s += __shfl_xor(s, 4);
        s += __shfl_xor(s, 8);
        if (lr == 0) atomicAdd(&logitsT[mm], s);
      }
    }
  }
}

// ---------- K2.5: per-b softmax stats (max, 1/den) ----------
__global__ void softstats(const float* __restrict__ logitsT, const int* __restrict__ mask,
                          float* __restrict__ stats) {
  __shared__ float red[8];
  const int b = blockIdx.x, t = threadIdx.x;
  float mx = -1e30f;
  for (int l = t; l < 2048; l += 256)
    if (mask[b * 2048 + l] != 0) mx = fmaxf(mx, logitsT[l * 64 + b]);
  #pragma unroll
  for (int o = 32; o > 0; o >>= 1) mx = fmaxf(mx, __shfl_xor(mx, o));
  if ((t & 63) == 0) red[t >> 6] = mx;
  __syncthreads();
  mx = fmaxf(fmaxf(red[0], red[1]), fmaxf(red[2], red[3]));
  float den = 0.f;
  for (int l = t; l < 2048; l += 256)
    if (mask[b * 2048 + l] != 0) den += __expf(logitsT[l * 64 + b] - mx);
  #pragma unroll
  for (int o = 32; o > 0; o >>= 1) den += __shfl_xor(den, o);
  if ((t & 63) == 0) red[4 + (t >> 6)] = den;
  __syncthreads();
  if (t == 0) {
    stats[b * 2] = mx;
    stats[b * 2 + 1] = 1.f / (red[4] + red[5] + red[6] + red[7]);
  }
}

// ---------- K3: weighted sum over masked rows (compacted bf16 via m2cm) ----------
__global__ void wsum_bf16(const short* __restrict__ A_c, const float* __restrict__ logitsT,
                          const int* __restrict__ mask, const float* __restrict__ stats,
                          const int* __restrict__ m2cm, float* __restrict__ out) {
  const int b = blockIdx.x >> 5;
  const int lc = blockIdx.x & 31;          // 32 chunks x 64 l
  const int t = threadIdx.x;
  const float mx = stats[b * 2], invd = stats[b * 2 + 1];
  const int h0 = t * 4;
  float4 a = {0.f, 0.f, 0.f, 0.f};
  for (int l = lc * 64; l < lc * 64 + 64; ++l) {
    if (mask[b * 2048 + l] == 0) continue;  // block-uniform branch
    const unsigned cm = (unsigned)m2cm[l * 64 + b];
    if (cm >= (unsigned)CAPROWS) continue;
    float w = __expf(logitsT[l * 64 + b] - mx) * invd;
    s16x4 v = *(const s16x4*)&A_c[((size_t)cm << 10) + h0];
    a.x += w * bf2f(v.x);
    a.y += w * bf2f(v.y);
    a.z += w * bf2f(v.z);
    a.w += w * bf2f(v.w);
  }
  atomicAdd(&out[b * 1024 + h0 + 0], a.x);
  atomicAdd(&out[b * 1024 + h0 + 1], a.y);
  atomicAdd(&out[b * 1024 + h0 + 2], a.z);
  atomicAdd(&out[b * 1024 + h0 + 3], a.w);
}

extern "C" void kernel_launch(void* const* d_in, const int* in_sizes, int n_in,
                              void* d_out, int out_size, void* d_ws, size_t ws_size,
                              hipStream_t stream) {
  const float* prev   = (const float*)d_in[0];   // [L,B,H] f32
  const float* hidden = (const float*)d_in[1];   // [B,H] f32
  const int*   mask   = (const int*)d_in[2];     // [B,L] i32
  const float* We     = (const float*)d_in[3];   // [HC,2H] f32
  const float* be     = (const float*)d_in[4];   // [HC] f32
  const float* Wv     = (const float*)d_in[5];   // [HC] f32
  float* out = (float*)d_out;                    // [1,B,H] f32

  char* ws = (char*)d_ws;
  size_t off = 0;
  short* A_c     = (short*)(ws + off); off += (size_t)CAPROWS * 1024 * 2;  // 192 MiB
  short* Wb2     = (short*)(ws + off); off += 2097152;                     // 2 MiB
  float* hidbias = (float*)(ws + off); off += 262144;
  float* logitsT = (float*)(ws + off); off += 524288;
  int*   cm2m    = (int*)  (ws + off); off += (size_t)CAPROWS * 4;
  int*   m2cm    = (int*)  (ws + off); off += 524288;
  int*   bases   = (int*)  (ws + off); off += 4096;
  float* stats   = (float*)(ws + off); off += 1024;

  // no hipMemsetAsync: logitsT zeroed in scan_mask, d_out zeroed in hidbias_kernel
  scan_mask<<<1, 512, 0, stream>>>(mask, bases, logitsT);
  gather_rows<<<512, 512, 0, stream>>>(prev, mask, bases, A_c, cm2m, m2cm);
  convert_we_pack<<<1024, 256, 0, stream>>>(We, Wb2);
  hidbias_kernel<<<64, 256, 0, stream>>>(We, hidden, be, hidbias, out);
  energy_gemm_2b<<<3072, 256, 0, stream>>>(A_c, Wb2, hidbias, Wv, bases, cm2m, logitsT);
  softstats<<<64, 256, 0, stream>>>(logitsT, mask, stats);
  wsum_bf16<<<2048, 256, 0, stream>>>(A_c, logitsT, mask, stats, m2cm, out);
}

// Round 12
// 486.475 us; speedup vs baseline: 1.0404x; 1.0404x over previous
//
#include <hip/hip_runtime.h>
#include <hip/hip_bf16.h>
#include <stdint.h>

// Sizes (fixed by the problem)
#define LDIM 2048
#define BDIM 64
#define HDIM 1024
#define HCDIM 1024
// Compacted rows (mask==1 only): M_c ~ Binomial(131072, .5) ~= 65536 +- 181.
#define CAPROWS 98304   // compacted-row capacity: 180 sigma above the mean

typedef __attribute__((ext_vector_type(8))) short short8;  // 8 bf16 (4 VGPRs)
typedef __attribute__((ext_vector_type(4))) short s16x4;
typedef __attribute__((ext_vector_type(4))) float f32x4;

static __device__ __forceinline__ short f2bf(float f) {
  union { float f; uint32_t u; } a; a.f = f;
  uint32_t r = a.u + 0x7fffu + ((a.u >> 16) & 1u);  // RNE
  return (short)(r >> 16);
}
static __device__ __forceinline__ float bf2f(short s) {
  union { uint32_t u; float f; } a;
  a.u = ((uint32_t)(unsigned short)s) << 16;
  return a.f;
}
static __device__ __forceinline__ float fast_tanh(float x) {
  x = fminf(15.f, fmaxf(-15.f, x));
  float e = __expf(2.f * x);
  return (e - 1.f) * __builtin_amdgcn_rcpf(e + 1.f);
}

// direct-to-LDS 16B async copy (gfx950); dest is wave-uniform base + lane*16
#define GL16(gp, lp) __builtin_amdgcn_global_load_lds(                           \
    (const __attribute__((address_space(1))) void*)(gp),                         \
    (__attribute__((address_space(3))) void*)(lp), 16, 0, 0)

// ---------- Ks: mask scan (1 block, 512 thr) + zero logitsT (fused, r11-verified) ----------
// Scan-ordered bases keep cm monotone in m -> L2-friendly m2cm/A_c reads (r6 vs r9: +11us).
__global__ void scan_mask(const int* __restrict__ mask, int* __restrict__ bases,
                          float* __restrict__ logitsT) {
  __shared__ int sc[512];
  const int t = threadIdx.x;
  const float4 z = {0.f, 0.f, 0.f, 0.f};
  #pragma unroll 4
  for (int i = 0; i < 64; ++i) *(float4*)&logitsT[t * 256 + i * 4] = z;
  int cnt = 0;
  #pragma unroll 8
  for (int b = 0; b < 64; ++b) {
    int4 v = *(const int4*)&mask[b * 2048 + t * 4];
    cnt += v.x + v.y + v.z + v.w;
  }
  sc[t] = cnt;
  __syncthreads();
  for (int off = 1; off < 512; off <<= 1) {
    int v = (t >= off) ? sc[t - off] : 0;
    __syncthreads();
    sc[t] += v;
    __syncthreads();
  }
  bases[t] = sc[t] - cnt;            // exclusive
  if (t == 511) bases[512] = sc[511];
}

// ---------- Kg: gather unmasked rows, f32 -> bf16 (512 blocks x 512 thr) ----------
__global__ void gather_rows(const float* __restrict__ prev, const int* __restrict__ mask,
                            const int* __restrict__ bases, short* __restrict__ A_c,
                            int* __restrict__ cm2m, int* __restrict__ m2cm) {
  __shared__ int smm[256];
  __shared__ int swt[4];
  const int c = blockIdx.x, t = threadIdx.x;
  const int base = bases[c];
  int bit = 0, p = 0, wv = 0;
  if (t < 256) {
    const int m = c * 256 + t;                 // l = m>>6, b = t&63
    bit = (mask[(t & 63) * 2048 + (m >> 6)] != 0);
    unsigned long long bal = __ballot(bit);
    const int lane = t & 63;
    wv = t >> 6;
    p = __popcll(bal & ((1ull << lane) - 1ull));
    if (lane == 0) swt[wv] = (int)__popcll(bal);
  }
  __syncthreads();
  if (t < 256 && bit) {
    int off = p;
    for (int i = 0; i < wv; ++i) off += swt[i];
    const int cm = base + off;
    smm[off] = t;
    if (cm < CAPROWS) {
      cm2m[cm] = c * 256 + t;
      m2cm[c * 256 + t] = cm;
    }
  }
  __syncthreads();
  const int cnt = swt[0] + swt[1] + swt[2] + swt[3];
  const int col = (t & 255) * 4;
  for (int r = (t >> 8); r < cnt; r += 2) {
    const int lm = smm[r];
    const float4 v = *(const float4*)(prev + (((size_t)(c * 256 + lm)) << 10) + col);
    if (base + r < CAPROWS) {
      s16x4 o = { f2bf(v.x), f2bf(v.y), f2bf(v.z), f2bf(v.w) };
      *(s16x4*)&A_c[(((size_t)(base + r)) << 10) + col] = o;
    }
  }
}

// ---------- K1: W_e[:, H:2H] (f32) -> Wb bf16 [HC][H] row-major (r6 GEMM layout) ----------
__global__ void convert_we(const float* __restrict__ We, short* __restrict__ Wb) {
  int g = blockIdx.x * 256 + threadIdx.x;
  int c = g >> 8;
  int j = (g & 255) * 4;
  float4 v = *(const float4*)(We + (size_t)c * 2048 + 1024 + j);
  s16x4 o = { f2bf(v.x), f2bf(v.y), f2bf(v.z), f2bf(v.w) };
  *(s16x4*)(Wb + (size_t)c * 1024 + j) = o;
}

// ---------- K0: hidbias[b][c] = W_e[c,:H]·hidden[b] + b_e[c]  (+ zero d_out, fused) ----------
__global__ void hidbias_kernel(const float* __restrict__ We, const float* __restrict__ hidden,
                               const float* __restrict__ be, float* __restrict__ hidbias,
                               float* __restrict__ out) {
  __shared__ float wrow[1024];
  int c0 = blockIdx.x * 16;
  int t = threadIdx.x;
  int b = t >> 2, q = t & 3;
  const float4 z = {0.f, 0.f, 0.f, 0.f};
  *(float4*)&out[blockIdx.x * 1024 + t * 4] = z;
  for (int ci = 0; ci < 16; ++ci) {
    int c = c0 + ci;
    *(float4*)&wrow[t * 4] = *(const float4*)&We[(size_t)c * 2048 + t * 4];
    __syncthreads();
    float s0 = 0.f, s1 = 0.f;
    const float* hb = hidden + b * 1024;
    #pragma unroll 8
    for (int j = 0; j < 256; j += 2) {
      int i0 = q + 4 * j;
      s0 += wrow[i0] * hb[i0];
      s1 += wrow[i0 + 4] * hb[i0 + 4];
    }
    float s = s0 + s1;
    s += __shfl_xor(s, 1);
    s += __shfl_xor(s, 2);
    if (q == 0) hidbias[b * 1024 + c] = s + be[c];
    __syncthreads();
  }
}

// ---------- K2: compacted-M GEMM, 256x256 tile, BK=32, 4-buffer pipeline ----------
// == round-6 champion kernel, unchanged (best measured: 467 us total).
// 8 waves (2M x 4N), wave tile 128x64. LDS = 4 bufs x (256x32 A + B) = 128 KiB.
// Prefetch depth 3; one s_barrier per K-step; counted vmcnt(8) keeps 2 stages
// (8 global_load_lds) in flight ACROSS the barrier — never drains in main loop.
// Chunk swizzle c' = q ^ ((row>>1)&3), rule-21 both-sides (0 conflicts, r5/r6).
// Grid 2048 fixed; mt = (bid>>5)*8+(bid&7), nt = (bid>>3)&3 -> n-siblings share
// an XCD; surviving m-tiles spread evenly after early-exit past Mc.
// NOTE (r7-r11): 8-phase interleave, 128^2 tile, B-from-L2 regs, and 256x128
// 2-blocks/CU ALL regressed vs this config — it is the measured local optimum.
__global__ __launch_bounds__(512) void energy_gemm_p6(
    const short* __restrict__ A_c, const short* __restrict__ Wb,
    const float* __restrict__ hidbias, const float* __restrict__ Wv,
    const int* __restrict__ bases, const int* __restrict__ cm2m,
    float* __restrict__ logitsT)
{
  __shared__ short As[4][256][32];   // 64 KiB
  __shared__ short Bs[4][256][32];   // 64 KiB
  __shared__ int sidx[256];
  const int Mc0 = bases[512];
  const int Mc = Mc0 < CAPROWS ? Mc0 : CAPROWS;
  const int mt = ((blockIdx.x >> 5) << 3) + (blockIdx.x & 7);
  const int nt = (blockIdx.x >> 3) & 3;
  if (mt * 256 >= Mc) return;
  const int m0 = mt * 256;
  const int n0 = nt * 256;

  const int tid = threadIdx.x;
  const int wave = tid >> 6, lane = tid & 63;
  const int q = lane >> 4, lr = lane & 15;
  const int wr = wave >> 2, wc = wave & 3;        // 2M x 4N wave grid

  // staging map: thread t -> rows r0, r0+128; 16B chunk (t&3) of a 64B row.
  // Source chunk pre-swizzled: (t&3) ^ ((r0>>1)&3)  (invariant under r0+128).
  const int r0 = tid >> 2;                        // 0..127
  const int c0s = (((tid & 3) ^ ((r0 >> 1) & 3))) * 8;
  const short* asrc = A_c + (size_t)(m0 + r0) * 1024 + c0s;
  const short* bsrc = Wb  + (size_t)(n0 + r0) * 1024 + c0s;

#define STAGE(buf, ks) do {                                                    \
    const int _ko = (ks) * 32;                                                 \
    GL16(asrc + _ko,          &As[buf][0][0] + tid * 8);                       \
    GL16(asrc + 131072 + _ko, &As[buf][0][0] + tid * 8 + 4096);                \
    GL16(bsrc + _ko,          &Bs[buf][0][0] + tid * 8);                       \
    GL16(bsrc + 131072 + _ko, &Bs[buf][0][0] + tid * 8 + 4096);                \
  } while (0)

  // swizzled read chunk: q ^ ((row>>1)&3); row = *+16*mi+lr so (row>>1)&3 = (lr>>1)&3
  const int crd = (q ^ ((lr >> 1) & 3)) * 8;

#define COMPUTE(buf) do {                                                      \
    short8 af[8], bfr[4];                                                      \
    _Pragma("unroll")                                                          \
    for (int mi = 0; mi < 8; ++mi)                                             \
      af[mi] = *(const short8*)&As[buf][wr * 128 + mi * 16 + lr][crd];         \
    _Pragma("unroll")                                                          \
    for (int ni = 0; ni < 4; ++ni)                                             \
      bfr[ni] = *(const short8*)&Bs[buf][wc * 64 + ni * 16 + lr][crd];         \
    __builtin_amdgcn_s_setprio(1);                                             \
    _Pragma("unroll")                                                          \
    for (int mi = 0; mi < 8; ++mi)                                             \
      _Pragma("unroll")                                                        \
      for (int ni = 0; ni < 4; ++ni)                                           \
        acc[mi][ni] = __builtin_amdgcn_mfma_f32_16x16x32_bf16(                 \
            af[mi], bfr[ni], acc[mi][ni], 0, 0, 0);                            \
    __builtin_amdgcn_s_setprio(0);                                             \
  } while (0)

#define VMW8() asm volatile("s_waitcnt vmcnt(8)" ::: "memory")
#define VMW4() asm volatile("s_waitcnt vmcnt(4)" ::: "memory")
#define VMW0() asm volatile("s_waitcnt vmcnt(0)" ::: "memory")
#define BAR()  asm volatile("s_barrier" ::: "memory")

  f32x4 acc[8][4];
  #pragma unroll
  for (int i = 0; i < 8; ++i)
    #pragma unroll
    for (int j = 0; j < 4; ++j) acc[i][j] = (f32x4){0.f, 0.f, 0.f, 0.f};

  STAGE(0, 0);
  STAGE(1, 1);
  STAGE(2, 2);

  #pragma unroll 4
  for (int ks = 0; ks < 28; ++ks) {
    VMW8(); BAR();
    STAGE((ks + 3) & 3, ks + 3);   // overwrites buf (ks-1)&3: reads done pre-barrier
    COMPUTE(ks & 3);
  }
  // tail: ks = 28..31 (stage 31 issued at ks=28; counts then drain 8 -> 4 -> 0)
  VMW8(); BAR(); STAGE(3, 31); COMPUTE(0);
  VMW8(); BAR(); COMPUTE(1);
  VMW4(); BAR(); COMPUTE(2);
  VMW0(); BAR(); COMPUTE(3);

#undef STAGE
#undef COMPUTE

  // Epilogue. D frag: col = lr (-> c), row = 4*q + reg (verified r1-r11).
  if (tid < 256) sidx[tid] = (m0 + tid < Mc) ? cm2m[m0 + tid] : -1;
  __syncthreads();

  float wv[4];
  #pragma unroll
  for (int ni = 0; ni < 4; ++ni) wv[ni] = Wv[n0 + wc * 64 + ni * 16 + lr];

  #pragma unroll
  for (int mi = 0; mi < 8; ++mi) {
    #pragma unroll
    for (int r = 0; r < 4; ++r) {
      const int row = wr * 128 + mi * 16 + 4 * q + r;   // within 256-row tile
      const int mm = sidx[row];                         // uniform across lr group
      if (mm >= 0) {
        const int b = mm & 63;
        float s = 0.f;
        #pragma unroll
        for (int ni = 0; ni < 4; ++ni) {
          const int c = n0 + wc * 64 + ni * 16 + lr;
          s += fast_tanh(acc[mi][ni][r] + hidbias[b * 1024 + c]) * wv[ni];
        }
        s += __shfl_xor(s, 1);
        s += __shfl_xor(s, 2);
        s += __shfl_xor(s, 4);
        s += __shfl_xor(s, 8);
        if (lr == 0) atomicAdd(&logitsT[mm], s);
      }
    }
  }
}

// ---------- K2.5: per-b softmax stats (max, 1/den) ----------
__global__ void softstats(const float* __restrict__ logitsT, const int* __restrict__ mask,
                          float* __restrict__ stats) {
  __shared__ float red[8];
  const int b = blockIdx.x, t = threadIdx.x;
  float mx = -1e30f;
  for (int l = t; l < 2048; l += 256)
    if (mask[b * 2048 + l] != 0) mx = fmaxf(mx, logitsT[l * 64 + b]);
  #pragma unroll
  for (int o = 32; o > 0; o >>= 1) mx = fmaxf(mx, __shfl_xor(mx, o));
  if ((t & 63) == 0) red[t >> 6] = mx;
  __syncthreads();
  mx = fmaxf(fmaxf(red[0], red[1]), fmaxf(red[2], red[3]));
  float den = 0.f;
  for (int l = t; l < 2048; l += 256)
    if (mask[b * 2048 + l] != 0) den += __expf(logitsT[l * 64 + b] - mx);
  #pragma unroll
  for (int o = 32; o > 0; o >>= 1) den += __shfl_xor(den, o);
  if ((t & 63) == 0) red[4 + (t >> 6)] = den;
  __syncthreads();
  if (t == 0) {
    stats[b * 2] = mx;
    stats[b * 2 + 1] = 1.f / (red[4] + red[5] + red[6] + red[7]);
  }
}

// ---------- K3: weighted sum over masked rows (compacted bf16 via m2cm) ----------
__global__ void wsum_bf16(const short* __restrict__ A_c, const float* __restrict__ logitsT,
                          const int* __restrict__ mask, const float* __restrict__ stats,
                          const int* __restrict__ m2cm, float* __restrict__ out) {
  const int b = blockIdx.x >> 5;
  const int lc = blockIdx.x & 31;          // 32 chunks x 64 l
  const int t = threadIdx.x;
  const float mx = stats[b * 2], invd = stats[b * 2 + 1];
  const int h0 = t * 4;
  float4 a = {0.f, 0.f, 0.f, 0.f};
  for (int l = lc * 64; l < lc * 64 + 64; ++l) {
    if (mask[b * 2048 + l] == 0) continue;  // block-uniform branch
    const unsigned cm = (unsigned)m2cm[l * 64 + b];
    if (cm >= (unsigned)CAPROWS) continue;
    float w = __expf(logitsT[l * 64 + b] - mx) * invd;
    s16x4 v = *(const s16x4*)&A_c[((size_t)cm << 10) + h0];
    a.x += w * bf2f(v.x);
    a.y += w * bf2f(v.y);
    a.z += w * bf2f(v.z);
    a.w += w * bf2f(v.w);
  }
  atomicAdd(&out[b * 1024 + h0 + 0], a.x);
  atomicAdd(&out[b * 1024 + h0 + 1], a.y);
  atomicAdd(&out[b * 1024 + h0 + 2], a.z);
  atomicAdd(&out[b * 1024 + h0 + 3], a.w);
}

extern "C" void kernel_launch(void* const* d_in, const int* in_sizes, int n_in,
                              void* d_out, int out_size, void* d_ws, size_t ws_size,
                              hipStream_t stream) {
  const float* prev   = (const float*)d_in[0];   // [L,B,H] f32
  const float* hidden = (const float*)d_in[1];   // [B,H] f32
  const int*   mask   = (const int*)d_in[2];     // [B,L] i32
  const float* We     = (const float*)d_in[3];   // [HC,2H] f32
  const float* be     = (const float*)d_in[4];   // [HC] f32
  const float* Wv     = (const float*)d_in[5];   // [HC] f32
  float* out = (float*)d_out;                    // [1,B,H] f32

  char* ws = (char*)d_ws;
  size_t off = 0;
  short* A_c     = (short*)(ws + off); off += (size_t)CAPROWS * 1024 * 2;  // 192 MiB
  short* Wb      = (short*)(ws + off); off += 2097152;                     // 2 MiB
  float* hidbias = (float*)(ws + off); off += 262144;
  float* logitsT = (float*)(ws + off); off += 524288;
  int*   cm2m    = (int*)  (ws + off); off += (size_t)CAPROWS * 4;
  int*   m2cm    = (int*)  (ws + off); off += 524288;
  int*   bases   = (int*)  (ws + off); off += 4096;
  float* stats   = (float*)(ws + off); off += 1024;

  // no memsets: logitsT zeroed in scan_mask, d_out zeroed in hidbias_kernel
  scan_mask<<<1, 512, 0, stream>>>(mask, bases, logitsT);
  gather_rows<<<512, 512, 0, stream>>>(prev, mask, bases, A_c, cm2m, m2cm);
  convert_we<<<1024, 256, 0, stream>>>(We, Wb);
  hidbias_kernel<<<64, 256, 0, stream>>>(We, hidden, be, hidbias, out);
  energy_gemm_p6<<<2048, 512, 0, stream>>>(A_c, Wb, hidbias, Wv, bases, cm2m, logitsT);
  softstats<<<64, 256, 0, stream>>>(logitsT, mask, stats);
  wsum_bf16<<<2048, 256, 0, stream>>>(A_c, logitsT, mask, stats, m2cm, out);
}

// Round 13
// 468.938 us; speedup vs baseline: 1.0793x; 1.0374x over previous
//
#include <hip/hip_runtime.h>
#include <hip/hip_bf16.h>
#include <stdint.h>

// Sizes (fixed by the problem)
#define LDIM 2048
#define BDIM 64
#define HDIM 1024
#define HCDIM 1024
// M = L*B = 131072 rows, natural order m = l*B + b (layout of prev_layer_outputs)
// Compacted rows (mask==1 only): M_c ~ Binomial(131072, .5) ~= 65536 +- 181.
#define CAPROWS 98304   // compacted-row capacity: 180 sigma above the mean

typedef __attribute__((ext_vector_type(8))) short short8;  // 8 bf16 (4 VGPRs)
typedef __attribute__((ext_vector_type(4))) short s16x4;
typedef __attribute__((ext_vector_type(4))) float f32x4;

static __device__ __forceinline__ short f2bf(float f) {
  union { float f; uint32_t u; } a; a.f = f;
  uint32_t r = a.u + 0x7fffu + ((a.u >> 16) & 1u);  // RNE
  return (short)(r >> 16);
}
static __device__ __forceinline__ float bf2f(short s) {
  union { uint32_t u; float f; } a;
  a.u = ((uint32_t)(unsigned short)s) << 16;
  return a.f;
}
static __device__ __forceinline__ float fast_tanh(float x) {
  x = fminf(15.f, fmaxf(-15.f, x));
  float e = __expf(2.f * x);
  return (e - 1.f) * __builtin_amdgcn_rcpf(e + 1.f);
}

// direct-to-LDS 16B async copy (gfx950); dest is wave-uniform base + lane*16
#define GL16(gp, lp) __builtin_amdgcn_global_load_lds(                           \
    (const __attribute__((address_space(1))) void*)(gp),                         \
    (__attribute__((address_space(3))) void*)(lp), 16, 0, 0)

// ---------- Ks: per-chunk mask counts + exclusive scan (1 block, 512 thr) ----------
// chunk c covers m in [c*256,(c+1)*256) => l in [4c,4c+4), all 64 b.
// bases[c] = exclusive prefix; bases[512] = M_c total.
// NOTE r12: do NOT fuse bulk zeroing here — a single block serializes 512 KB of
// writes on one CU while the whole GPU waits on bases (+10-20 us). Memsets are
// device-wide and effectively free.
__global__ void scan_mask(const int* __restrict__ mask, int* __restrict__ bases) {
  __shared__ int sc[512];
  const int t = threadIdx.x;
  int cnt = 0;
  #pragma unroll 8
  for (int b = 0; b < 64; ++b) {
    int4 v = *(const int4*)&mask[b * 2048 + t * 4];
    cnt += v.x + v.y + v.z + v.w;
  }
  sc[t] = cnt;
  __syncthreads();
  for (int off = 1; off < 512; off <<= 1) {
    int v = (t >= off) ? sc[t - off] : 0;
    __syncthreads();
    sc[t] += v;
    __syncthreads();
  }
  bases[t] = sc[t] - cnt;            // exclusive
  if (t == 511) bases[512] = sc[511];
}

// ---------- Kg: gather unmasked rows, f32 -> bf16 (512 blocks x 512 thr) ----------
// Writes A_c[cm][1024] bf16, cm2m[cm] = m, m2cm[m] = cm (unmasked m only).
// Scan-ordered bases keep cm monotone in m -> L2-friendly reads downstream (r9: +11us).
__global__ void gather_rows(const float* __restrict__ prev, const int* __restrict__ mask,
                            const int* __restrict__ bases, short* __restrict__ A_c,
                            int* __restrict__ cm2m, int* __restrict__ m2cm) {
  __shared__ int smm[256];   // local row index (within chunk) per compact slot
  __shared__ int swt[4];     // per-wave bit totals
  const int c = blockIdx.x, t = threadIdx.x;
  const int base = bases[c];
  int bit = 0, p = 0, wv = 0;
  if (t < 256) {
    const int m = c * 256 + t;                 // l = m>>6, b = t&63
    bit = (mask[(t & 63) * 2048 + (m >> 6)] != 0);
    unsigned long long bal = __ballot(bit);
    const int lane = t & 63;
    wv = t >> 6;
    p = __popcll(bal & ((1ull << lane) - 1ull));
    if (lane == 0) swt[wv] = (int)__popcll(bal);
  }
  __syncthreads();
  if (t < 256 && bit) {
    int off = p;
    for (int i = 0; i < wv; ++i) off += swt[i];
    const int cm = base + off;
    smm[off] = t;
    if (cm < CAPROWS) {
      cm2m[cm] = c * 256 + t;
      m2cm[c * 256 + t] = cm;
    }
  }
  __syncthreads();
  const int cnt = swt[0] + swt[1] + swt[2] + swt[3];
  // cooperative row copy: 512 threads = 2 rows per iteration (256 thr x 16B each)
  const int col = (t & 255) * 4;
  for (int r = (t >> 8); r < cnt; r += 2) {
    const int lm = smm[r];
    const float4 v = *(const float4*)(prev + (((size_t)(c * 256 + lm)) << 10) + col);
    if (base + r < CAPROWS) {
      s16x4 o = { f2bf(v.x), f2bf(v.y), f2bf(v.z), f2bf(v.w) };
      *(s16x4*)&A_c[(((size_t)(base + r)) << 10) + col] = o;
    }
  }
}

// ---------- K1: W_e[:, H:2H] (f32) -> Wb bf16 [HC][H] ----------
__global__ void convert_we(const float* __restrict__ We, short* __restrict__ Wb) {
  int g = blockIdx.x * 256 + threadIdx.x;
  int c = g >> 8;
  int j = (g & 255) * 4;
  float4 v = *(const float4*)(We + (size_t)c * 2048 + 1024 + j);
  s16x4 o = { f2bf(v.x), f2bf(v.y), f2bf(v.z), f2bf(v.w) };
  *(s16x4*)(Wb + (size_t)c * 1024 + j) = o;
}

// ---------- K0: hidbias[b][c] = W_e[c,:H]·hidden[b] + b_e[c] ----------
__global__ void hidbias_kernel(const float* __restrict__ We, const float* __restrict__ hidden,
                               const float* __restrict__ be, float* __restrict__ hidbias) {
  __shared__ float wrow[1024];
  int c0 = blockIdx.x * 16;
  int t = threadIdx.x;
  int b = t >> 2, q = t & 3;
  for (int ci = 0; ci < 16; ++ci) {
    int c = c0 + ci;
    *(float4*)&wrow[t * 4] = *(const float4*)&We[(size_t)c * 2048 + t * 4];
    __syncthreads();
    float s0 = 0.f, s1 = 0.f;
    const float* hb = hidden + b * 1024;
    #pragma unroll 8
    for (int j = 0; j < 256; j += 2) {
      int i0 = q + 4 * j;
      s0 += wrow[i0] * hb[i0];
      s1 += wrow[i0 + 4] * hb[i0 + 4];
    }
    float s = s0 + s1;
    s += __shfl_xor(s, 1);
    s += __shfl_xor(s, 2);
    if (q == 0) hidbias[b * 1024 + c] = s + be[c];
    __syncthreads();
  }
}

// ---------- K2: compacted-M GEMM, 256x256 tile, BK=32, 4-buffer pipeline ----------
// The measured champion (round 6: 467 us total). 8 waves (2M x 4N), wave tile
// 128x64. LDS = 4 bufs x (256x32 A + B) = 128 KiB. Prefetch depth 3; one
// s_barrier per K-step; counted vmcnt(8) keeps 2 stages (8 global_load_lds) in
// flight ACROSS the barrier — never drains in the main loop. Chunk swizzle
// c' = q ^ ((row>>1)&3), rule-21 both-sides (0 bank conflicts, verified r5/r6).
// Grid 2048 fixed; mt = (bid>>5)*8+(bid&7), nt = (bid>>3)&3 -> an m-tile's 4
// n-siblings share an XCD; live m-tiles spread evenly after early-exit past Mc.
// Structure variants ALL measured worse from here: 8-phase interleave (r7 +22us),
// 128^2 tile (r8 +58us), B-from-L2 regs (r10 +17us), 256x128 2blk/CU (r11 +39us).
__global__ __launch_bounds__(512) void energy_gemm_p6(
    const short* __restrict__ A_c, const short* __restrict__ Wb,
    const float* __restrict__ hidbias, const float* __restrict__ Wv,
    const int* __restrict__ bases, const int* __restrict__ cm2m,
    float* __restrict__ logitsT)
{
  __shared__ short As[4][256][32];   // 64 KiB
  __shared__ short Bs[4][256][32];   // 64 KiB
  __shared__ int sidx[256];
  const int Mc0 = bases[512];
  const int Mc = Mc0 < CAPROWS ? Mc0 : CAPROWS;
  const int mt = ((blockIdx.x >> 5) << 3) + (blockIdx.x & 7);
  const int nt = (blockIdx.x >> 3) & 3;
  if (mt * 256 >= Mc) return;
  const int m0 = mt * 256;
  const int n0 = nt * 256;

  const int tid = threadIdx.x;
  const int wave = tid >> 6, lane = tid & 63;
  const int q = lane >> 4, lr = lane & 15;
  const int wr = wave >> 2, wc = wave & 3;        // 2M x 4N wave grid

  // staging map: thread t -> rows r0, r0+128; 16B chunk (t&3) of a 64B row.
  // Source chunk pre-swizzled: (t&3) ^ ((r0>>1)&3)  (invariant under r0+128).
  const int r0 = tid >> 2;                        // 0..127
  const int c0s = (((tid & 3) ^ ((r0 >> 1) & 3))) * 8;
  const short* asrc = A_c + (size_t)(m0 + r0) * 1024 + c0s;
  const short* bsrc = Wb  + (size_t)(n0 + r0) * 1024 + c0s;

#define STAGE(buf, ks) do {                                                    \
    const int _ko = (ks) * 32;                                                 \
    GL16(asrc + _ko,          &As[buf][0][0] + tid * 8);                       \
    GL16(asrc + 131072 + _ko, &As[buf][0][0] + tid * 8 + 4096);                \
    GL16(bsrc + _ko,          &Bs[buf][0][0] + tid * 8);                       \
    GL16(bsrc + 131072 + _ko, &Bs[buf][0][0] + tid * 8 + 4096);                \
  } while (0)

  // swizzled read chunk: q ^ ((row>>1)&3); row = *+16*mi+lr so (row>>1)&3 = (lr>>1)&3
  const int crd = (q ^ ((lr >> 1) & 3)) * 8;

#define COMPUTE(buf) do {                                                      \
    short8 af[8], bfr[4];                                                      \
    _Pragma("unroll")                                                          \
    for (int mi = 0; mi < 8; ++mi)                                             \
      af[mi] = *(const short8*)&As[buf][wr * 128 + mi * 16 + lr][crd];         \
    _Pragma("unroll")                                                          \
    for (int ni = 0; ni < 4; ++ni)                                             \
      bfr[ni] = *(const short8*)&Bs[buf][wc * 64 + ni * 16 + lr][crd];         \
    __builtin_amdgcn_s_setprio(1);                                             \
    _Pragma("unroll")                                                          \
    for (int mi = 0; mi < 8; ++mi)                                             \
      _Pragma("unroll")                                                        \
      for (int ni = 0; ni < 4; ++ni)                                           \
        acc[mi][ni] = __builtin_amdgcn_mfma_f32_16x16x32_bf16(                 \
            af[mi], bfr[ni], acc[mi][ni], 0, 0, 0);                            \
    __builtin_amdgcn_s_setprio(0);                                             \
  } while (0)

#define VMW8() asm volatile("s_waitcnt vmcnt(8)" ::: "memory")
#define VMW4() asm volatile("s_waitcnt vmcnt(4)" ::: "memory")
#define VMW0() asm volatile("s_waitcnt vmcnt(0)" ::: "memory")
#define BAR()  asm volatile("s_barrier" ::: "memory")

  f32x4 acc[8][4];
  #pragma unroll
  for (int i = 0; i < 8; ++i)
    #pragma unroll
    for (int j = 0; j < 4; ++j) acc[i][j] = (f32x4){0.f, 0.f, 0.f, 0.f};

  STAGE(0, 0);
  STAGE(1, 1);
  STAGE(2, 2);

  #pragma unroll 4
  for (int ks = 0; ks < 28; ++ks) {
    VMW8(); BAR();
    STAGE((ks + 3) & 3, ks + 3);   // overwrites buf (ks-1)&3: reads done pre-barrier
    COMPUTE(ks & 3);
  }
  // tail: ks = 28..31 (stage 31 issued at ks=28; counts then drain 8 -> 4 -> 0)
  VMW8(); BAR(); STAGE(3, 31); COMPUTE(0);
  VMW8(); BAR(); COMPUTE(1);
  VMW4(); BAR(); COMPUTE(2);
  VMW0(); BAR(); COMPUTE(3);

#undef STAGE
#undef COMPUTE

  // Epilogue. D frag: col = lr (-> c), row = 4*q + reg (verified r1-r12).
  if (tid < 256) sidx[tid] = (m0 + tid < Mc) ? cm2m[m0 + tid] : -1;
  __syncthreads();

  float wv[4];
  #pragma unroll
  for (int ni = 0; ni < 4; ++ni) wv[ni] = Wv[n0 + wc * 64 + ni * 16 + lr];

  #pragma unroll
  for (int mi = 0; mi < 8; ++mi) {
    #pragma unroll
    for (int r = 0; r < 4; ++r) {
      const int row = wr * 128 + mi * 16 + 4 * q + r;   // within 256-row tile
      const int mm = sidx[row];                         // uniform across lr group
      if (mm >= 0) {
        const int b = mm & 63;
        float s = 0.f;
        #pragma unroll
        for (int ni = 0; ni < 4; ++ni) {
          const int c = n0 + wc * 64 + ni * 16 + lr;
          s += fast_tanh(acc[mi][ni][r] + hidbias[b * 1024 + c]) * wv[ni];
        }
        s += __shfl_xor(s, 1);
        s += __shfl_xor(s, 2);
        s += __shfl_xor(s, 4);
        s += __shfl_xor(s, 8);
        if (lr == 0) atomicAdd(&logitsT[mm], s);
      }
    }
  }
}

// ---------- K2.5: per-b softmax stats (max, 1/den) ----------
__global__ void softstats(const float* __restrict__ logitsT, const int* __restrict__ mask,
                          float* __restrict__ stats) {
  __shared__ float red[8];
  const int b = blockIdx.x, t = threadIdx.x;
  float mx = -1e30f;
  for (int l = t; l < 2048; l += 256)
    if (mask[b * 2048 + l] != 0) mx = fmaxf(mx, logitsT[l * 64 + b]);
  #pragma unroll
  for (int o = 32; o > 0; o >>= 1) mx = fmaxf(mx, __shfl_xor(mx, o));
  if ((t & 63) == 0) red[t >> 6] = mx;
  __syncthreads();
  mx = fmaxf(fmaxf(red[0], red[1]), fmaxf(red[2], red[3]));
  float den = 0.f;
  for (int l = t; l < 2048; l += 256)
    if (mask[b * 2048 + l] != 0) den += __expf(logitsT[l * 64 + b] - mx);
  #pragma unroll
  for (int o = 32; o > 0; o >>= 1) den += __shfl_xor(den, o);
  if ((t & 63) == 0) red[4 + (t >> 6)] = den;
  __syncthreads();
  if (t == 0) {
    stats[b * 2] = mx;
    stats[b * 2 + 1] = 1.f / (red[4] + red[5] + red[6] + red[7]);
  }
}

// ---------- K3: weighted sum over masked rows (compacted bf16 via m2cm) ----------
__global__ void wsum_bf16(const short* __restrict__ A_c, const float* __restrict__ logitsT,
                          const int* __restrict__ mask, const float* __restrict__ stats,
                          const int* __restrict__ m2cm, float* __restrict__ out) {
  const int b = blockIdx.x >> 5;
  const int lc = blockIdx.x & 31;          // 32 chunks x 64 l
  const int t = threadIdx.x;
  const float mx = stats[b * 2], invd = stats[b * 2 + 1];
  const int h0 = t * 4;
  float4 a = {0.f, 0.f, 0.f, 0.f};
  for (int l = lc * 64; l < lc * 64 + 64; ++l) {
    if (mask[b * 2048 + l] == 0) continue;  // block-uniform branch
    const unsigned cm = (unsigned)m2cm[l * 64 + b];
    if (cm >= (unsigned)CAPROWS) continue;  // never taken in practice
    float w = __expf(logitsT[l * 64 + b] - mx) * invd;
    s16x4 v = *(const s16x4*)&A_c[((size_t)cm << 10) + h0];
    a.x += w * bf2f(v.x);
    a.y += w * bf2f(v.y);
    a.z += w * bf2f(v.z);
    a.w += w * bf2f(v.w);
  }
  atomicAdd(&out[b * 1024 + h0 + 0], a.x);
  atomicAdd(&out[b * 1024 + h0 + 1], a.y);
  atomicAdd(&out[b * 1024 + h0 + 2], a.z);
  atomicAdd(&out[b * 1024 + h0 + 3], a.w);
}

extern "C" void kernel_launch(void* const* d_in, const int* in_sizes, int n_in,
                              void* d_out, int out_size, void* d_ws, size_t ws_size,
                              hipStream_t stream) {
  const float* prev   = (const float*)d_in[0];   // [L,B,H] f32
  const float* hidden = (const float*)d_in[1];   // [B,H] f32
  const int*   mask   = (const int*)d_in[2];     // [B,L] i32
  const float* We     = (const float*)d_in[3];   // [HC,2H] f32
  const float* be     = (const float*)d_in[4];   // [HC] f32
  const float* Wv     = (const float*)d_in[5];   // [HC] f32
  float* out = (float*)d_out;                    // [1,B,H] f32

  char* ws = (char*)d_ws;
  size_t off = 0;
  short* A_c     = (short*)(ws + off); off += (size_t)CAPROWS * 1024 * 2;  // 192 MiB
  short* Wb      = (short*)(ws + off); off += 2097152;                     // 2 MiB
  float* hidbias = (float*)(ws + off); off += 262144;
  float* logitsT = (float*)(ws + off); off += 524288;
  int*   cm2m    = (int*)  (ws + off); off += (size_t)CAPROWS * 4;         // 384 KiB
  int*   m2cm    = (int*)  (ws + off); off += 524288;
  int*   bases   = (int*)  (ws + off); off += 4096;
  float* stats   = (float*)(ws + off); off += 1024;

  hipMemsetAsync(d_out, 0, (size_t)out_size * sizeof(float), stream);
  hipMemsetAsync(logitsT, 0, 131072 * sizeof(float), stream);
  scan_mask<<<1, 512, 0, stream>>>(mask, bases);
  gather_rows<<<512, 512, 0, stream>>>(prev, mask, bases, A_c, cm2m, m2cm);
  convert_we<<<1024, 256, 0, stream>>>(We, Wb);
  hidbias_kernel<<<64, 256, 0, stream>>>(We, hidden, be, hidbias);
  energy_gemm_p6<<<2048, 512, 0, stream>>>(A_c, Wb, hidbias, Wv, bases, cm2m, logitsT);
  softstats<<<64, 256, 0, stream>>>(logitsT, mask, stats);
  wsum_bf16<<<2048, 256, 0, stream>>>(A_c, logitsT, mask, stats, m2cm, out);
}